// Round 5
// baseline (259.886 us; speedup 1.0000x reference)
//
#include <hip/hip_runtime.h>
#include <stdint.h>

// RNN1: B=4096,T=256,E=27,H=64.
// a_{t+1} = tanh(a_t @ Waa^T + x_t @ Wax^T + ba), x_t = word[:,t-1,:] (0 at t=0)
// y[:,t,:] = a_{t+1} @ Wy^T + by
//
// Round 5 = round 4 + (a) weight fragments PINNED in VGPRs via opaque asm
// (round 4's VGPR_Count=112 proved the compiler re-fetched all weight frags
// from cache every step: 2400 cyc/step, all pipes idle), (b) waves_per_eu(1,1)
// so the allocator budgets 512 VGPRs, (c) x prefetch deepened to 4 steps,
// (d) MFMA terms rebalanced into depth-3/2/2 chains.
//
// TRANSPOSED single-wave design (validated r4, absmax 0.0078): one 64-lane
// wave owns 16 batch rows and the full H=64 chain; state^T = Waa @ a^T with
// weights as A (rows m, k pre-permuted by sigma) and state as B (n=batch).
// D layout (n=lane&15, m=4*lg+reg) IS the next step's sigma B-frag ->
// zero-cost feedback: no LDS, no barriers, no cross-lane ops in the loop.
// sigma_f(lg,j) = (j<4 ? 4*lg+j : 12+4*lg+j) + 32*f.
// Numerics: split-bf16 state (hi+lo), 3 products (WH*sH, WH*sL, WL*sH);
// x and Wy single bf16.

#define B_ 4096
#define T_ 256
#define E_ 27
#define H_ 64
#define WROW_ (H_ + E_)  // 91

typedef __bf16 bf16x8 __attribute__((ext_vector_type(8)));
typedef float f32x4 __attribute__((ext_vector_type(4)));
typedef unsigned int u32x4 __attribute__((ext_vector_type(4)));

static __device__ __forceinline__ unsigned pk2(float a, float b) {
  unsigned short ua = __builtin_bit_cast(unsigned short, (__bf16)a);
  unsigned short ub = __builtin_bit_cast(unsigned short, (__bf16)b);
  return (unsigned)ua | ((unsigned)ub << 16);
}
static __device__ __forceinline__ unsigned pkh(__bf16 a, __bf16 b) {
  unsigned short ua = __builtin_bit_cast(unsigned short, a);
  unsigned short ub = __builtin_bit_cast(unsigned short, b);
  return (unsigned)ua | ((unsigned)ub << 16);
}
static __device__ __forceinline__ float fast_tanh(float z) {
  // tanh(z) = 1 - 2/(exp(2z)+1); exp->inf / ->0 limits give +/-1 correctly
  float e = __expf(2.0f * z);
  float r = __builtin_amdgcn_rcpf(e + 1.0f);
  return __builtin_fmaf(-2.0f, r, 1.0f);
}
static __device__ __forceinline__ f32x4 MF(u32x4 a, u32x4 b, f32x4 c) {
  return __builtin_amdgcn_mfma_f32_16x16x32_bf16(
      __builtin_bit_cast(bf16x8, a), __builtin_bit_cast(bf16x8, b), c, 0, 0, 0);
}

__global__ __launch_bounds__(64)
__attribute__((amdgpu_waves_per_eu(1, 1))) void rnn_fused(
    const float* __restrict__ word, const float* __restrict__ Wa,
    const float* __restrict__ ba, const float* __restrict__ Wy,
    const float* __restrict__ by, float* __restrict__ out) {
  const int lane = threadIdx.x;
  const int p16 = lane & 15;  // batch row within group (n) / weight row (m)
  const int lg = lane >> 4;   // k-slot group
  const int rb = (int)blockIdx.x * 16;

  const float* const wrow = word + (size_t)(rb + p16) * (T_ * E_);
  float* const pout = out + (size_t)(rb + p16) * (T_ * E_);

  // ---- x prefetch sets (4-deep): pf0 = x(t=0) = 0; pf1..pf3 <- word[0..2] --
  float pf0[8], pf1[8], pf2[8], pf3[8];
#pragma unroll
  for (int k = 0; k < 8; ++k) {
    const int e = 8 * lg + k;
    pf0[k] = 0.f;
    pf1[k] = (e < E_) ? wrow[0 * E_ + 8 * lg + k] : 0.f;
    pf2[k] = (e < E_) ? wrow[1 * E_ + 8 * lg + k] : 0.f;
    pf3[k] = (e < E_) ? wrow[2 * E_ + 8 * lg + k] : 0.f;
  }

  // ---- weight fragments, pre-permuted by sigma ----
  u32x4 WH[4][2], WL[4][2], WX[4], WY[2][2];
  f32x4 BAv[4], BYv[2];
#pragma unroll
  for (int mt = 0; mt < 4; ++mt) {
    const float* base = Wa + (16 * mt + p16) * WROW_;
#pragma unroll
    for (int f = 0; f < 2; ++f) {
#pragma unroll
      for (int v = 0; v < 4; ++v) {
        const int j = 2 * v;
        const int c = ((j < 4) ? (4 * lg + j) : (12 + 4 * lg + j)) + 32 * f;
        const float w0 = base[c], w1 = base[c + 1];
        const __bf16 h0 = (__bf16)w0, h1 = (__bf16)w1;
        WH[mt][f][v] = pkh(h0, h1);
        WL[mt][f][v] = pk2(w0 - (float)h0, w1 - (float)h1);
      }
    }
#pragma unroll
    for (int v = 0; v < 4; ++v) {  // Wax, natural k = e
      const int e0 = 8 * lg + 2 * v, e1 = e0 + 1;
      const float w0 = (e0 < E_) ? base[H_ + e0] : 0.f;
      const float w1 = (e1 < E_) ? base[H_ + e1] : 0.f;
      WX[mt][v] = pk2(w0, w1);
    }
  }
#pragma unroll
  for (int my = 0; my < 2; ++my) {  // Wy rows e = 16*my + p16, sigma k-cols
    const int e = 16 * my + p16;
    const bool valid = (e < E_);
    const float* rp = Wy + e * H_;
#pragma unroll
    for (int f = 0; f < 2; ++f) {
#pragma unroll
      for (int v = 0; v < 4; ++v) {
        const int j = 2 * v;
        const int c = ((j < 4) ? (4 * lg + j) : (12 + 4 * lg + j)) + 32 * f;
        const float w0 = valid ? rp[c] : 0.f;
        const float w1 = valid ? rp[c + 1] : 0.f;
        WY[my][f][v] = pk2(w0, w1);
      }
    }
  }
#pragma unroll
  for (int mt = 0; mt < 4; ++mt) {
    f32x4 t;
#pragma unroll
    for (int r = 0; r < 4; ++r) t[r] = ba[16 * mt + 4 * lg + r];
    BAv[mt] = t;
  }
#pragma unroll
  for (int my = 0; my < 2; ++my) {
    f32x4 t;
#pragma unroll
    for (int r = 0; r < 4; ++r) {
      const int e = 16 * my + 4 * lg + r;
      t[r] = (e < E_) ? by[e] : 0.f;
    }
    BYv[my] = t;
  }

  // ---- PIN all loop-invariant fragments in VGPRs (opaque to the compiler:
  // cannot be rematerialized or sunk into the loop; r4's VGPR=112 showed the
  // compiler otherwise re-fetches them every step) ----
#pragma unroll
  for (int mt = 0; mt < 4; ++mt) {
    asm volatile("" : "+v"(WH[mt][0]), "+v"(WH[mt][1]), "+v"(WL[mt][0]),
                      "+v"(WL[mt][1]), "+v"(WX[mt]), "+v"(BAv[mt]));
  }
  asm volatile("" : "+v"(WY[0][0]), "+v"(WY[0][1]), "+v"(WY[1][0]),
                    "+v"(WY[1][1]), "+v"(BYv[0]), "+v"(BYv[1]));

  // ---- state frags (sigma layout), a0 = 0 ----
  u32x4 sH0 = {0u, 0u, 0u, 0u}, sH1 = sH0, sL0 = sH0, sL1 = sH0;

#define STEP(t, PF)                                                           \
  {                                                                           \
    u32x4 xf;                                                                 \
    xf[0] = pk2(PF[0], PF[1]);                                                \
    xf[1] = pk2(PF[2], PF[3]);                                                \
    xf[2] = pk2(PF[4], PF[5]);                                                \
    xf[3] = pk2(PF[6], PF[7]);                                                \
    if ((t) + 3 < T_) { /* prefetch word[t+3] = x_{t+4}, consumed 4 steps on */\
      const float* p = wrow + ((t) + 3) * E_;                                 \
      _Pragma("unroll") for (int k = 0; k < 8; ++k) {                         \
        const int e = 8 * lg + k;                                             \
        PF[k] = (e < E_) ? p[8 * lg + k] : 0.f;                               \
      }                                                                       \
    }                                                                         \
    f32x4 acc[4];                                                             \
    _Pragma("unroll") for (int mt = 0; mt < 4; ++mt) {                        \
      f32x4 c0 = BAv[mt];                                                     \
      c0 = MF(WH[mt][0], sH0, c0);                                            \
      c0 = MF(WH[mt][1], sH1, c0);                                            \
      c0 = MF(WX[mt], xf, c0);                                                \
      f32x4 c1 = MF(WH[mt][0], sL0, (f32x4){0.f, 0.f, 0.f, 0.f});             \
      c1 = MF(WH[mt][1], sL1, c1);                                            \
      f32x4 c2 = MF(WL[mt][0], sH0, (f32x4){0.f, 0.f, 0.f, 0.f});             \
      c2 = MF(WL[mt][1], sH1, c2);                                            \
      acc[mt] = c0 + (c1 + c2);                                               \
    }                                                                         \
    unsigned hw[4][2], lw[4][2];                                              \
    _Pragma("unroll") for (int mt = 0; mt < 4; ++mt) {                        \
      const float t0 = fast_tanh(acc[mt][0]);                                 \
      const float t1 = fast_tanh(acc[mt][1]);                                 \
      const float t2 = fast_tanh(acc[mt][2]);                                 \
      const float t3 = fast_tanh(acc[mt][3]);                                 \
      const __bf16 h0 = (__bf16)t0, h1 = (__bf16)t1;                          \
      const __bf16 h2 = (__bf16)t2, h3 = (__bf16)t3;                          \
      hw[mt][0] = pkh(h0, h1);                                                \
      hw[mt][1] = pkh(h2, h3);                                                \
      lw[mt][0] = pk2(t0 - (float)h0, t1 - (float)h1);                        \
      lw[mt][1] = pk2(t2 - (float)h2, t3 - (float)h3);                        \
    }                                                                         \
    sH0[0] = hw[0][0]; sH0[1] = hw[0][1]; sH0[2] = hw[1][0]; sH0[3] = hw[1][1];\
    sH1[0] = hw[2][0]; sH1[1] = hw[2][1]; sH1[2] = hw[3][0]; sH1[3] = hw[3][1];\
    sL0[0] = lw[0][0]; sL0[1] = lw[0][1]; sL0[2] = lw[1][0]; sL0[3] = lw[1][1];\
    sL1[0] = lw[2][0]; sL1[1] = lw[2][1]; sL1[2] = lw[3][0]; sL1[3] = lw[3][1];\
    f32x4 y0 = BYv[0];                                                        \
    y0 = MF(WY[0][0], sH0, y0);                                               \
    y0 = MF(WY[0][1], sH1, y0);                                               \
    f32x4 y1 = BYv[1];                                                        \
    y1 = MF(WY[1][0], sH0, y1);                                               \
    y1 = MF(WY[1][1], sH1, y1);                                               \
    float* po = pout + (t)*E_;                                                \
    _Pragma("unroll") for (int r = 0; r < 4; ++r) po[4 * lg + r] = y0[r];     \
    _Pragma("unroll") for (int r = 0; r < 4; ++r) {                           \
      const int e = 16 + 4 * lg + r;                                          \
      if (e < E_) po[e] = y1[r];                                              \
    }                                                                         \
  }

  for (int t = 0; t < T_; t += 4) {
    STEP(t, pf0);
    STEP(t + 1, pf1);
    STEP(t + 2, pf2);
    STEP(t + 3, pf3);
  }
#undef STEP
}

extern "C" void kernel_launch(void* const* d_in, const int* in_sizes, int n_in,
                              void* d_out, int out_size, void* d_ws,
                              size_t ws_size, hipStream_t stream) {
  const float* word = (const float*)d_in[0];
  const float* Wa = (const float*)d_in[1];
  const float* ba = (const float*)d_in[2];
  const float* Wy = (const float*)d_in[3];
  const float* by = (const float*)d_in[4];
  float* out = (float*)d_out;
  rnn_fused<<<dim3(B_ / 16), dim3(64), 0, stream>>>(word, Wa, ba, Wy, by, out);
}